// Round 8
// baseline (318.414 us; speedup 1.0000x reference)
//
#include <hip/hip_runtime.h>
#include <hip/hip_bf16.h>

#define H_ 64
#define W_ 2048
#define HWsz (H_*W_)
#define CIN 64
#define CTOT 68
#define COUT 64

typedef float  f32x2  __attribute__((ext_vector_type(2)));
typedef float  f32x4  __attribute__((ext_vector_type(4)));
typedef float  f32x16 __attribute__((ext_vector_type(16)));
typedef short  s16x8  __attribute__((ext_vector_type(8)));
typedef _Float16 f16x8 __attribute__((ext_vector_type(8)));

__device__ __forceinline__ unsigned short f2bf(float f) {
    unsigned u = __builtin_bit_cast(unsigned, f);
    unsigned r = u + 0x7fffu + ((u >> 16) & 1u);   // RNE; inputs finite
    return (unsigned short)(r >> 16);
}

__device__ __forceinline__ unsigned pack2bf(float a, float b) {
    __hip_bfloat162 h = __float22bfloat162_rn(float2{a, b});   // v_cvt_pk_bf16_f32
    unsigned u;
    __builtin_memcpy(&u, &h, 4);
    return u;
}

// async 16B/lane global->LDS copy: wave-uniform LDS base, per-lane global src.
__device__ __forceinline__ void gl_lds16(const unsigned short* g, unsigned short* l) {
    __builtin_amdgcn_global_load_lds(
        (const __attribute__((address_space(1))) unsigned int*)g,
        (__attribute__((address_space(3))) unsigned int*)l,
        16, 0, 0);
}

// ---------------- prep: Wagg -> bf16 A-frags; fold BN1; MLP A-frags (f16) ----------------
// frag layout (both A and B operands of 32x32x16): lane l holds dim=(l&31),
// k=(l>>5)*8+j. C: col=lane&31, row=(r&3)+8*(r>>2)+4*(lane>>5).
__global__ __launch_bounds__(256) void prep_bw(
    const float* __restrict__ Wagg,
    const float* __restrict__ W1, const float* __restrict__ g1,
    const float* __restrict__ b1, const float* __restrict__ m1,
    const float* __restrict__ v1, const float* __restrict__ W2,
    unsigned short* __restrict__ BwS, float* __restrict__ Wfold,
    unsigned short* __restrict__ AfS, float* __restrict__ w2tab)
{
    int tid = threadIdx.x;
    if (blockIdx.x == 0) {
        if (tid < 64) {
            float s1 = g1[tid] * rsqrtf(v1[tid] + 1e-5f);
#pragma unroll
            for (int m = 0; m < 4; ++m) Wfold[tid*8 + m] = W1[tid*4 + m] * s1;
            Wfold[tid*8 + 4] = b1[tid] - m1[tid]*s1;
            Wfold[tid*8 + 5] = W2[tid];
            Wfold[tid*8 + 6] = 0.f;
            Wfold[tid*8 + 7] = 0.f;
        }
        // MLP A-frags (f16): AfS[mh][lane][j]; ch = mh*32+(l&31), k=(l>>5)*8+j
        // k<4: W1f[ch][k]; k==4: b1f[ch]; else 0.
        if (tid >= 64 && tid < 192) {
            int idx = tid - 64;
            int mh = idx >> 6, l = idx & 63;
            int ch = mh*32 + (l & 31);
            int kb = (l >> 5) * 8;
            float s1 = g1[ch] * rsqrtf(v1[ch] + 1e-5f);
            unsigned short o8[8];
#pragma unroll
            for (int j = 0; j < 8; ++j) {
                int k = kb + j;
                float val = (k < 4) ? W1[ch*4 + k] * s1
                          : (k == 4 ? b1[ch] - m1[ch]*s1 : 0.f);
                _Float16 hv = (_Float16)val;
                o8[j] = __builtin_bit_cast(unsigned short, hv);
            }
#pragma unroll
            for (int j = 0; j < 8; ++j) AfS[(size_t)idx*8 + j] = o8[j];
        }
        // W2 permuted to C-row order: w2tab[mh*32+hi*16+r] = W2[mh*32+(r&3)+8*(r>>2)+4*hi]
        if (tid >= 192) {
            int t = tid - 192;
            int mh = t >> 5, hi = (t >> 4) & 1, r = t & 15;
            int ch = mh*32 + (r & 3) + 8*(r >> 2) + 4*hi;
            w2tab[t] = W2[ch];
        }
        __syncthreads();
        if (tid == 0) {
            float s = 0.f;
            for (int c = 0; c < 64; ++c) s += fmaxf(Wfold[c*8 + 4], 0.f) * Wfold[c*8 + 5];
            Wfold[512] = s;
        }
    }
    int idx = blockIdx.x * 256 + tid;
    if (idx < 4608) {
        int lane = idx & 63;
        int rest = idx >> 6;
        int nt = rest & 1;
        int ks = (rest >> 1) & 3;
        int k9 = rest >> 3;
        int o  = nt*32 + (lane & 31);
        int ch = ks*16 + (lane >> 5)*8;
        const float* src = Wagg + (size_t)o*(9*CIN) + k9*64 + ch;
        s16x8 v8;
#pragma unroll
        for (int j = 0; j < 8; ++j) v8[j] = (short)f2bf(src[j]);
        *(s16x8*)(BwS + (size_t)idx*8) = v8;
    }
}

// ---------------- sw_k: MFMA logit MLP + softmax -> sws; feats -> xg ----------------
// Block 512 thr, tile = 2 rows x 64 px. wave = (rowq = wv>>2, tg = wv&3).
// Logits via mfma_f32_32x32x16_f16: A = Wfold-frags (K=5: 4 pos dims + bias-carrying 1),
// B = d-frags (f16, lanes<32 carry K), C reduced with relu x W2-permuted table.
// xg transform issued after the reduce (regs free), before the barrier.
__global__ __launch_bounds__(512, 6) void sw_k(
    const float* __restrict__ x, const int* __restrict__ mask,
    const float* __restrict__ Wfold, const float* __restrict__ b2p,
    const unsigned short* __restrict__ AfS, const float* __restrict__ w2tab,
    float* __restrict__ sws, unsigned short* __restrict__ xg)
{
    __shared__ float sw[2][9][64];

    const int tid = threadIdx.x;
    const int bx = blockIdx.x, by = blockIdx.y;
    const int b = by >> 5, h0 = (by & 31) << 1;
    const int w0 = bx << 6;
    const int lane = tid & 63, wv = tid >> 6;

    const float* xp = x + (size_t)b*CTOT*HWsz;         // pos channels 0..3
    const float* xf = x + ((size_t)b*CTOT + 4)*HWsz;   // feat channels
    const int*   mk = mask + (size_t)b*HWsz;

    const int px = lane, gw = w0 + px;
    const int rowq = wv >> 2, tg = wv & 3;
    const int h = h0 + rowq;
    const int ka = 2*tg + (tg >> 1);        // tg 0..3 -> taps {0,1},{2,3},{5,6},{7,8}

    // A-frags for the MLP (16B per lane, L2-resident)
    f16x8 Af0 = *(const f16x8*)(AfS + (size_t)lane*8);
    f16x8 Af1 = *(const f16x8*)(AfS + 512 + (size_t)lane*8);

    float pc[4];
#pragma unroll
    for (int ch = 0; ch < 4; ++ch) pc[ch] = xp[(size_t)ch*HWsz + (size_t)h*W_ + gw];

    f32x2 dd[4]; f32x2 mu;
#pragma unroll
    for (int i = 0; i < 2; ++i) {
        int k = ka + i;
        int r = k/3 - 1, d = k%3 - 1;
        int ih = h + r, iw = gw + d;
        bool ok = ((unsigned)ih < (unsigned)H_) && ((unsigned)iw < (unsigned)W_);
        int ihc = min(max(ih, 0), H_-1);
        int iwc = min(max(iw, 0), W_-1);
        mu[i] = ok ? (float)mk[(size_t)ihc*W_ + iwc] : 0.f;
#pragma unroll
        for (int ch = 0; ch < 4; ++ch) {
            float p = xp[(size_t)ch*HWsz + (size_t)ihc*W_ + iwc];
            dd[ch][i] = (ok ? p : 0.f) - pc[ch];   // reference zero-pads pn
        }
    }

    // partner px-half values (lane^32)
    float ddp[4][2], mup2[2];
#pragma unroll
    for (int j = 0; j < 4; ++j)
#pragma unroll
        for (int i = 0; i < 2; ++i) ddp[j][i] = __shfl_xor(dd[j][i], 32);
    mup2[0] = __shfl_xor(mu[0], 32);
    mup2[1] = __shfl_xor(mu[1], 32);

    // B-frags: tp = i*2+p (tap i, px-half p). Lanes<32 carry k=0..4.
    const bool lo = lane < 32;
    const _Float16 hz = (_Float16)0.f;
    const _Float16 h1 = lo ? (_Float16)1.f : hz;
    f16x8 Bf[4];
#pragma unroll
    for (int i = 0; i < 2; ++i)
#pragma unroll
        for (int p = 0; p < 2; ++p) {
            f16x8 f;
#pragma unroll
            for (int j = 0; j < 4; ++j) {
                float v = p ? ddp[j][i] : dd[j][i];
                f[j] = lo ? (_Float16)v : hz;
            }
            f[4] = h1; f[5] = hz; f[6] = hz; f[7] = hz;
            Bf[i*2 + p] = f;
        }

    // MFMA + relu x W2 reduce (mh outer to bound live registers)
    const int hi = lane >> 5;
    const f32x16 fz16 = {0.f,0.f,0.f,0.f,0.f,0.f,0.f,0.f,0.f,0.f,0.f,0.f,0.f,0.f,0.f,0.f};
    float acc[4] = {0.f, 0.f, 0.f, 0.f};
#pragma unroll
    for (int mh = 0; mh < 2; ++mh) {
        const float* wp = w2tab + mh*32 + hi*16;
        f32x4 wq[4];
#pragma unroll
        for (int q = 0; q < 4; ++q) wq[q] = *(const f32x4*)(wp + 4*q);
        f16x8 A = mh ? Af1 : Af0;
#pragma unroll
        for (int tp = 0; tp < 4; ++tp) {
            f32x16 C = __builtin_amdgcn_mfma_f32_32x32x16_f16(A, Bf[tp], fz16, 0, 0, 0);
#pragma unroll
            for (int r = 0; r < 16; ++r)
                acc[tp] = fmaf(fmaxf(C[r], 0.f), wq[r >> 2][r & 3], acc[tp]);
        }
    }
    float b2v = b2p[0];
#pragma unroll
    for (int tp = 0; tp < 4; ++tp) {
        float full = acc[tp] + __shfl_xor(acc[tp], 32);
        int i = tp >> 1, p = tp & 1;
        float lw = (full + b2v) * (p ? mup2[i] : mu[i]);
        if (lo) sw[rowq][ka + i][p*32 + lane] = lw;
    }

    // --- xg transform (after reduce: registers free) ---
    float tv[2][8];
#pragma unroll
    for (int cc = 0; cc < 2; ++cc) {
        int id = tid + (cc << 9);
        int rq = id >> 9, g = (id >> 6) & 7, pxx = id & 63;
        const float* src = xf + (size_t)(g*8)*HWsz + (size_t)(h0 + rq)*W_ + w0 + pxx;
#pragma unroll
        for (int j = 0; j < 8; ++j) tv[cc][j] = src[(size_t)j*HWsz];
    }
#pragma unroll
    for (int cc = 0; cc < 2; ++cc) {
        int id = tid + (cc << 9);
        int rq = id >> 9, g = (id >> 6) & 7, pxx = id & 63;
        uint4 q;
        q.x = pack2bf(tv[cc][0], tv[cc][1]); q.y = pack2bf(tv[cc][2], tv[cc][3]);
        q.z = pack2bf(tv[cc][4], tv[cc][5]); q.w = pack2bf(tv[cc][6], tv[cc][7]);
        *(uint4*)(xg + ((((size_t)(b*H_ + h0 + rq)*8 + g)*W_) + w0 + pxx)*8) = q;
    }
    __syncthreads();

    // softmax over 9 taps (128 threads) -> global sws
    if (tid < 128) {
        int rq = tid >> 6, p2 = tid & 63;
        float mu4 = (float)mk[(size_t)(h0 + rq)*W_ + w0 + p2];
        float lgv[9];
#pragma unroll
        for (int k = 0; k < 9; ++k) if (k != 4) lgv[k] = sw[rq][k][p2];
        lgv[4] = (Wfold[512] + b2v) * mu4;
        float mx = -1e30f;
#pragma unroll
        for (int k = 0; k < 9; ++k) mx = fmaxf(mx, lgv[k]);
        float s = 0.f, e[9];
#pragma unroll
        for (int k = 0; k < 9; ++k) { e[k] = __expf(lgv[k] - mx); s += e[k]; }
        float inv = 1.f / s;
        float* dst = sws + ((size_t)(b*H_ + h0 + rq)*9)*W_ + w0 + p2;
#pragma unroll
        for (int k = 0; k < 9; ++k) dst[(size_t)k*W_] = e[k] * inv;
    }
}

// ---------------- agg_k: async-stage xg -> weighted MFMA -> BN2 epilogue ----------------
// (unchanged from R7: ~26 us, near traffic roofline)
__global__ __launch_bounds__(256, 4) void agg_k(
    const unsigned short* __restrict__ xg, const float* __restrict__ sws,
    const unsigned short* __restrict__ BwS,
    const float* __restrict__ g2, const float* __restrict__ bb2,
    const float* __restrict__ m2, const float* __restrict__ v2,
    float* __restrict__ out)
{
    __shared__ __align__(16) unsigned short fe[4][8][66][8];   // 33,792 B
    __shared__ __align__(16) float sbn[2][64];                 //    512 B

    const int tid = threadIdx.x;
    const int bx = blockIdx.x, by = blockIdx.y;
    const int b = by >> 5, h0 = (by & 31) << 1;
    const int w0 = bx << 6;
    const int lane = tid & 63, wv = tid >> 6;

    // --- interior staging: async, 8 (r,g) tasks per wave, 1KB each ---
#pragma unroll
    for (int it = 0; it < 8; ++it) {
        int u = it*4 + wv;                  // wave-uniform
        int g = u & 7, r = u >> 3;
        int gr = h0 - 1 + r;
        if ((unsigned)gr < (unsigned)H_) {
            const unsigned short* src =
                xg + ((((size_t)(b*H_ + gr)*8 + g)*W_) + w0 + lane)*8;
            gl_lds16(src, &fe[r][g][1][0]);
        } else {
            uint4 z = {0u, 0u, 0u, 0u};
            *(uint4*)&fe[r][g][1 + lane][0] = z;
        }
    }
    // --- halo: 64 tasks (2 cols x 8 g x 4 r), 16B each ---
    if (tid < 64) {
        int c2 = tid & 1, g = (tid >> 1) & 7, r = tid >> 4;
        int gr = h0 - 1 + r, gc = w0 - 1 + c2*65;
        uint4 q = {0u, 0u, 0u, 0u};
        if (((unsigned)gr < (unsigned)H_) && ((unsigned)gc < (unsigned)W_))
            q = *(const uint4*)(xg + ((((size_t)(b*H_ + gr)*8 + g)*W_) + gc)*8);
        *(uint4*)&fe[r][g][c2*65][0] = q;
    }
    // BN2 table: tid in [64,128)
    if (tid >= 64 && tid < 128) {
        int o = tid - 64;
        float sc = g2[o] * rsqrtf(v2[o] + 1e-5f);
        sbn[0][o] = sc;
        sbn[1][o] = bb2[o] - m2[o]*sc;
    }

    // prefetch softmax weights for this wave (both halves, 9 taps) - registers
    const int nt = wv & 1, rh = wv >> 1;
    const int l31 = lane & 31, l5 = lane >> 5;
    const int hC = h0 + rh;
    const float* swp = sws + ((size_t)(b*H_ + hC)*9)*W_ + w0 + l31;
    float swr[2][9];
#pragma unroll
    for (int half = 0; half < 2; ++half)
#pragma unroll
        for (int k9 = 0; k9 < 9; ++k9)
            swr[half][k9] = swp[(size_t)k9*W_ + half*32];

    __syncthreads();

    // --- MFMA: A=Wagg fragments (L2), B=feats (LDS) ---
    const f32x16 fz16 = {0.f,0.f,0.f,0.f,0.f,0.f,0.f,0.f,0.f,0.f,0.f,0.f,0.f,0.f,0.f,0.f};
    f32x16 fin[2] = {fz16, fz16};

#pragma unroll
    for (int k9 = 0; k9 < 9; ++k9) {
        const int rr = rh + k9/3;            // fe row (fe[0] = global row h0-1)
        const int dwp = k9 % 3;

        s16x8 aw[4];
#pragma unroll
        for (int ks = 0; ks < 4; ++ks)
            aw[ks] = *(const s16x8*)(BwS + (size_t)((((k9<<2) + ks)*2 + nt) << 9) + lane*8);

#pragma unroll
        for (int half = 0; half < 2; ++half) {
            int col = half*32 + l31 + dwp;   // 1 + px + (dwp-1)
            f32x16 tmp = fz16;
#pragma unroll
            for (int ks = 0; ks < 4; ++ks) {
                s16x8 bfr = *(const s16x8*)&fe[rr][ks*2 + l5][col][0];
                tmp = __builtin_amdgcn_mfma_f32_32x32x16_bf16(aw[ks], bfr, tmp, 0, 0, 0);
            }
            float wsc = swr[half][k9];
#pragma unroll
            for (int c = 0; c < 16; ++c) fin[half][c] += wsc * tmp[c];
        }
    }

    // --- epilogue: BN2 + ReLU, coalesced dword stores (128B segments) ---
    int obase = nt*32 + 4*l5;
#pragma unroll
    for (int half = 0; half < 2; ++half) {
        float* od = out + (((size_t)b*COUT + obase)*H_ + hC)*W_ + w0 + half*32 + l31;
#pragma unroll
        for (int v = 0; v < 4; ++v) {
            f32x4 sc4 = *(const f32x4*)&sbn[0][obase + 8*v];
            f32x4 tc4 = *(const f32x4*)&sbn[1][obase + 8*v];
#pragma unroll
            for (int c = 0; c < 4; ++c)
                od[(size_t)(8*v + c)*HWsz] =
                    fmaxf(fmaf(fin[half][4*v + c], sc4[c], tc4[c]), 0.f);
        }
    }
}

extern "C" void kernel_launch(void* const* d_in, const int* in_sizes, int n_in,
                              void* d_out, int out_size, void* d_ws, size_t ws_size,
                              hipStream_t stream)
{
    const float* x    = (const float*)d_in[0];
    const int*   mask = (const int*)d_in[1];
    const float* W1   = (const float*)d_in[2];
    const float* g1   = (const float*)d_in[3];
    const float* b1   = (const float*)d_in[4];
    const float* m1   = (const float*)d_in[5];
    const float* v1   = (const float*)d_in[6];
    const float* W2   = (const float*)d_in[7];
    const float* b2   = (const float*)d_in[8];
    const float* Wagg = (const float*)d_in[9];
    const float* g2   = (const float*)d_in[10];
    const float* bb2  = (const float*)d_in[11];
    const float* m2   = (const float*)d_in[12];
    const float* v2   = (const float*)d_in[13];
    float* outp = (float*)d_out;

    char* ws = (char*)d_ws;
    unsigned short* BwS   = (unsigned short*)(ws + 0);       // 73,728 B
    float*          Wfold = (float*)(ws + 73728);            //  2,052 B
    unsigned short* AfS   = (unsigned short*)(ws + 76800);   //  2,048 B
    float*          w2tab = (float*)(ws + 78848);            //    256 B
    float*          sws   = (float*)(ws + 81920);            // 9,437,184 B
    unsigned short* xg    = (unsigned short*)(ws + 9519104); // 33,554,432 B

    hipLaunchKernelGGL(prep_bw, dim3(18), dim3(256), 0, stream,
                       Wagg, W1, g1, b1, m1, v1, W2, BwS, Wfold, AfS, w2tab);
    hipLaunchKernelGGL(sw_k, dim3(W_/64, 64), dim3(512), 0, stream,
                       x, mask, Wfold, b2, AfS, w2tab, sws, xg);
    hipLaunchKernelGGL(agg_k, dim3(W_/64, 64), dim3(256), 0, stream,
                       xg, sws, BwS, g2, bb2, m2, v2, outp);
}